// Round 12
// baseline (319.982 us; speedup 1.0000x reference)
//
#include <hip/hip_runtime.h>

#define DIM 128
#define NG 64
#define NCLS 10
#define CAP 64             // padded-CSR slots per node
#define WSZ 256            // nodes per window
#define NWMAX 512          // max windows (n <= 131072)
#define CAPB 8192          // edges per window bucket (mean 4096, +64 sigma)
#define EPB 4096           // edges per bucket_kernel block (391 blocks -> all CUs covered)
#define HL 4               // local readout accumulator graphs per block
#define WTP 68             // LDS Wt row stride in words (272 B: frag reads 2-way alias = free)

typedef __attribute__((ext_vector_type(8))) short s8v;
typedef __attribute__((ext_vector_type(4))) float f4v;

__device__ inline unsigned short f2bf(float f) {
    unsigned int u = __float_as_uint(f);
    unsigned int r = (u + 0x7fffu + ((u >> 16) & 1u)) >> 16;
    return (unsigned short)r;
}
__device__ inline unsigned int pack2bf(float a, float b) {
    return ((unsigned int)f2bf(b) << 16) | (unsigned int)f2bf(a);
}

// ---------------- Phase A: bucket edges + folded prep work ----------------
// Cursors are 0-based (memset by host); addresses add w*CAPB. First blocks also do the
// former prep_kernel work (Wt cast/transpose, hg zero, zero-row init) - saves a dispatch.
__global__ __launch_bounds__(1024) void bucket_kernel(const int* __restrict__ src,
                                                      const int* __restrict__ dst,
                                                      int* curD, int* curS,
                                                      int* __restrict__ bucketD,
                                                      unsigned char* __restrict__ bucketS,
                                                      const float* __restrict__ W1,
                                                      const float* __restrict__ W2,
                                                      unsigned short* __restrict__ Wt1,
                                                      unsigned short* __restrict__ Wt2,
                                                      float* __restrict__ hg,
                                                      uint4* hb4, uint4* x1b4,
                                                      int e, int nw, int n) {
    __shared__ int histD[NWMAX];
    __shared__ int histS[NWMAX];
    int t = threadIdx.x;
    int gtid = blockIdx.x * 1024 + t;
    // folded prep (independent of bucketing)
    if (gtid < 32768) {
        int which = gtid >> 14;
        int i = gtid & 16383;
        int c = i >> 7, k = i & 127;
        (which ? Wt2 : Wt1)[i] = f2bf((which ? W2 : W1)[k * 128 + c]);
    }
    if (gtid < NG * DIM) hg[gtid] = 0.0f;
    if (gtid < 16) {
        uint4 z = make_uint4(0, 0, 0, 0);
        hb4[(size_t)n * 16 + gtid] = z;
        x1b4[(size_t)n * 16 + gtid] = z;
    }
    for (int i = t; i < nw; i += 1024) { histD[i] = 0; histS[i] = 0; }
    __syncthreads();
    int lo = blockIdx.x * EPB;
    int hi = min(e, lo + EPB);
    for (int i = lo + t * 4; i < hi; i += 4096) {
        int4 d4 = *(const int4*)&dst[i];
        int4 s4 = *(const int4*)&src[i];
        atomicAdd(&histD[d4.x >> 8], 1); atomicAdd(&histS[s4.x >> 8], 1);
        atomicAdd(&histD[d4.y >> 8], 1); atomicAdd(&histS[s4.y >> 8], 1);
        atomicAdd(&histD[d4.z >> 8], 1); atomicAdd(&histS[s4.z >> 8], 1);
        atomicAdd(&histD[d4.w >> 8], 1); atomicAdd(&histS[s4.w >> 8], 1);
    }
    __syncthreads();
    for (int i = t; i < nw; i += 1024) {
        int hd = histD[i], hs = histS[i];
        histD[i] = hd ? atomicAdd(&curD[i], hd) : 0;   // 0-based within window
        histS[i] = hs ? atomicAdd(&curS[i], hs) : 0;
    }
    __syncthreads();
    for (int i = lo + t * 4; i < hi; i += 4096) {
        int4 d4 = *(const int4*)&dst[i];
        int4 s4 = *(const int4*)&src[i];
#pragma unroll
        for (int j = 0; j < 4; ++j) {
            int d = (&d4.x)[j], s = (&s4.x)[j];
            int sd = atomicAdd(&histD[d >> 8], 1);
            bucketD[(size_t)(d >> 8) * CAPB + sd] = (s << 8) | (d & 255);
            int ss = atomicAdd(&histS[s >> 8], 1);
            bucketS[(size_t)(s >> 8) * CAPB + ss] = (unsigned char)(s & 255);
        }
    }
}

// ---------------- Phase B: window CSR fill + degrees + rs + FUSED h cast; 1024 threads --------
__global__ __launch_bounds__(1024) void window_kernel(const int* __restrict__ curD,
                                                      const int* __restrict__ curS,
                                                      const int* __restrict__ bucketD,
                                                      const unsigned char* __restrict__ bucketS,
                                                      const float* __restrict__ h,
                                                      int* __restrict__ cnt_in,
                                                      float* __restrict__ rs_in,
                                                      float* __restrict__ rs_out,
                                                      int* __restrict__ colx_pad,
                                                      uint4* __restrict__ hb4, int n) {
    __shared__ int cin[WSZ];
    __shared__ int cout[WSZ];
    __shared__ float rsO_s[WSZ];
    int w = blockIdx.x, t = threadIdx.x;
    if (t < WSZ) { cin[t] = 0; cout[t] = 0; }
    __syncthreads();
    size_t base = (size_t)w * CAPB;
    int nE = min(curD[w], CAPB);
    for (int i = t; i < nE; i += 1024) {
        int v = bucketD[base + i];
        int d8 = v & 255;
        int slot = atomicAdd(&cin[d8], 1);
        if (slot < CAP) colx_pad[(((w << 8) + d8) << 6) + slot] = v >> 8;
    }
    int nS = min(curS[w], CAPB);
    for (int i = t; i < nS; i += 1024) atomicAdd(&cout[bucketS[base + i]], 1);
    __syncthreads();
    if (t < WSZ) {
        int node = (w << 8) + t;
        if (node < n) {
            int c = cin[t];
            cnt_in[node] = c;
            rs_in[node] = rsqrtf(fmaxf((float)c, 1.0f));
            float ro = rsqrtf(fmaxf((float)cout[t], 1.0f));
            rs_out[node] = ro;
            rsO_s[t] = ro;
            int cc = min(c, CAP);
            int c8 = min((cc + 7) & ~7, CAP);   // pad to multiple of 8 (zero-row n)
            for (int s = cc; s < c8; ++s) colx_pad[((size_t)node << 6) + s] = n;
        }
    }
    __syncthreads();
    for (int idx = t; idx < WSZ * 16; idx += 1024) {
        int rl = idx >> 4, sub = idx & 15;
        int nd = (w << 8) + rl;
        if (nd < n) {
            float s = rsO_s[rl];
            float4 a = ((const float4*)h)[(size_t)nd * 32 + sub * 2];
            float4 b = ((const float4*)h)[(size_t)nd * 32 + sub * 2 + 1];
            uint4 o;
            o.x = pack2bf(a.x * s, a.y * s);
            o.y = pack2bf(a.z * s, a.w * s);
            o.z = pack2bf(b.x * s, b.y * s);
            o.w = pack2bf(b.z * s, b.w * s);
            hb4[(size_t)nd * 16 + sub] = o;
        }
    }
}

// ---------------- SpMM gather, dwordx4, pad-8 slots ----------------
__global__ __launch_bounds__(256) void spmm_bf16(const uint4* __restrict__ xb4,
                                                 const int* __restrict__ cnt_in,
                                                 const int* __restrict__ colx_pad,
                                                 const float* __restrict__ rs_in,
                                                 uint4* __restrict__ yb4, int n) {
    int node = (blockIdx.x * 256 + threadIdx.x) >> 6;
    int lane = threadIdx.x & 63;
    if (node >= n) return;
    int g = lane >> 4, sub = lane & 15;
    int cnt = min(cnt_in[node], CAP);
    int cnt8 = min((cnt + 7) & ~7, CAP);
    int myc = colx_pad[((size_t)node << 6) + ((lane < cnt8) ? lane : 0)];
    float acc[8] = {0.f, 0.f, 0.f, 0.f, 0.f, 0.f, 0.f, 0.f};
    int j = 0;
    for (; j + 16 <= cnt8; j += 16) {
        uint4 v[4];
#pragma unroll
        for (int b = 0; b < 4; ++b) {
            int c = __shfl(myc, j + 4 * b + g);
            v[b] = xb4[(size_t)c * 16 + sub];
        }
#pragma unroll
        for (int b = 0; b < 4; ++b) {
            acc[0] += __uint_as_float(v[b].x << 16);
            acc[1] += __uint_as_float(v[b].x & 0xffff0000u);
            acc[2] += __uint_as_float(v[b].y << 16);
            acc[3] += __uint_as_float(v[b].y & 0xffff0000u);
            acc[4] += __uint_as_float(v[b].z << 16);
            acc[5] += __uint_as_float(v[b].z & 0xffff0000u);
            acc[6] += __uint_as_float(v[b].w << 16);
            acc[7] += __uint_as_float(v[b].w & 0xffff0000u);
        }
    }
    if (j < cnt8) {
        int c0 = __shfl(myc, j + g);
        int c1 = __shfl(myc, j + 4 + g);
        uint4 v0 = xb4[(size_t)c0 * 16 + sub];
        uint4 v1 = xb4[(size_t)c1 * 16 + sub];
#pragma unroll
        for (int b = 0; b < 2; ++b) {
            uint4 v = b ? v1 : v0;
            acc[0] += __uint_as_float(v.x << 16);
            acc[1] += __uint_as_float(v.x & 0xffff0000u);
            acc[2] += __uint_as_float(v.y << 16);
            acc[3] += __uint_as_float(v.y & 0xffff0000u);
            acc[4] += __uint_as_float(v.z << 16);
            acc[5] += __uint_as_float(v.z & 0xffff0000u);
            acc[6] += __uint_as_float(v.w << 16);
            acc[7] += __uint_as_float(v.w & 0xffff0000u);
        }
    }
#pragma unroll
    for (int i = 0; i < 8; ++i) {
        acc[i] += __shfl_xor(acc[i], 16);
        acc[i] += __shfl_xor(acc[i], 32);
    }
    if (g == 0) {
        float w = rs_in[node];
        uint4 o;
        o.x = pack2bf(acc[0] * w, acc[1] * w);
        o.y = pack2bf(acc[2] * w, acc[3] * w);
        o.z = pack2bf(acc[4] * w, acc[5] * w);
        o.w = pack2bf(acc[6] * w, acc[7] * w);
        yb4[(size_t)node * 16 + sub] = o;
    }
}

// ---------------- stage Wt (32KB) into LDS with padded stride ----------------
__device__ inline void stage_wt(const uint4* __restrict__ Wt4, unsigned int* WtL, int t) {
#pragma unroll
    for (int i = 0; i < 8; ++i) {
        int q = t + 256 * i;           // 0..2047
        int row = q >> 4, col4 = q & 15;
        *(uint4*)&WtL[row * WTP + col4 * 4] = Wt4[q];
    }
}

// ---------------- layer-1 MM: 128 rows/block (2 row-groups per Wt staging) ----------------
__global__ __launch_bounds__(256) void mm_mfma(const unsigned char* __restrict__ A,
                                               const uint4* __restrict__ Wt4,
                                               const float* __restrict__ bias,
                                               const float* __restrict__ rs_out,
                                               unsigned short* __restrict__ out, int n) {
    __shared__ unsigned int WtL[128 * WTP];   // 34.8 KB
    int t = threadIdx.x;
    stage_wt(Wt4, WtL, t);
    int wave = t >> 6, lane = t & 63;
    int m = lane & 15, q = lane >> 4;
    __syncthreads();
#pragma unroll
    for (int rg = 0; rg < 2; ++rg) {
        int r0 = (int)blockIdx.x * 128 + rg * 64 + wave * 16;
        if (r0 >= n) break;
        int arow = min(r0 + m, n - 1);
        f4v acc[8];
#pragma unroll
        for (int c = 0; c < 8; ++c) acc[c] = (f4v){0.f, 0.f, 0.f, 0.f};
#pragma unroll
        for (int k0 = 0; k0 < 4; ++k0) {
            s8v a = *(const s8v*)(A + (size_t)arow * 256 + k0 * 64 + q * 16);
#pragma unroll
            for (int c = 0; c < 8; ++c) {
                s8v b = *(const s8v*)&WtL[(c * 16 + m) * WTP + k0 * 16 + q * 4];
                acc[c] = __builtin_amdgcn_mfma_f32_16x16x32_bf16(a, b, acc[c], 0, 0, 0);
            }
        }
#pragma unroll
        for (int c = 0; c < 8; ++c) {
            float bv = bias[c * 16 + m];
#pragma unroll
            for (int r = 0; r < 4; ++r) {
                int row = r0 + q * 4 + r;
                if (row < n) {
                    float val = fmaxf(acc[c][r] + bv, 0.0f);
                    out[(size_t)row * 128 + c * 16 + m] = f2bf(val * rs_out[row]);
                }
            }
        }
    }
}

// ---------------- layer-2 MM with FUSED mean-readout numerator, 128 rows/block ----------------
__global__ __launch_bounds__(256) void mm_mfma_readout(const unsigned char* __restrict__ A,
                                                       const uint4* __restrict__ Wt4,
                                                       const float* __restrict__ bias,
                                                       const int* __restrict__ gid,
                                                       float* __restrict__ hg, int n) {
    __shared__ unsigned int WtL[128 * WTP];   // 34.8 KB
    __shared__ float hgloc[HL][DIM];          // 2 KB
    int t = threadIdx.x;
    stage_wt(Wt4, WtL, t);
    for (int i = t; i < HL * DIM; i += 256) ((float*)hgloc)[i] = 0.0f;
    int wave = t >> 6, lane = t & 63;
    int m = lane & 15, q = lane >> 4;
    int b0 = (int)blockIdx.x * 128;
    int gid0 = gid[min(b0, n - 1)];
    __syncthreads();
#pragma unroll
    for (int rg = 0; rg < 2; ++rg) {
        int r0 = b0 + rg * 64 + wave * 16;
        if (r0 >= n) break;
        int arow = min(r0 + m, n - 1);
        f4v acc[8];
#pragma unroll
        for (int c = 0; c < 8; ++c) acc[c] = (f4v){0.f, 0.f, 0.f, 0.f};
#pragma unroll
        for (int k0 = 0; k0 < 4; ++k0) {
            s8v a = *(const s8v*)(A + (size_t)arow * 256 + k0 * 64 + q * 16);
#pragma unroll
            for (int c = 0; c < 8; ++c) {
                s8v b = *(const s8v*)&WtL[(c * 16 + m) * WTP + k0 * 16 + q * 4];
                acc[c] = __builtin_amdgcn_mfma_f32_16x16x32_bf16(a, b, acc[c], 0, 0, 0);
            }
        }
        int gfirst = gid[min(r0, n - 1)];
        int glast = gid[min(r0 + 15, n - 1)];
        bool uni = (gfirst == glast) && (r0 + 15 < n);
        if (uni) {
            int gl = gfirst - gid0;
#pragma unroll
            for (int c = 0; c < 8; ++c) {
                float bv = bias[c * 16 + m];
                float s = fmaxf(acc[c][0] + bv, 0.0f) + fmaxf(acc[c][1] + bv, 0.0f) +
                          fmaxf(acc[c][2] + bv, 0.0f) + fmaxf(acc[c][3] + bv, 0.0f);
                s += __shfl_xor(s, 16);
                s += __shfl_xor(s, 32);
                if (q == 0) {
                    if (gl < HL)
                        atomicAdd(&hgloc[gl][c * 16 + m], s);
                    else
                        atomicAdd(&hg[(size_t)gfirst * DIM + c * 16 + m], s);
                }
            }
        } else {
#pragma unroll
            for (int r = 0; r < 4; ++r) {
                int row = r0 + q * 4 + r;
                if (row < n) {
                    int g = gid[row];
                    int gl = g - gid0;
#pragma unroll
                    for (int c = 0; c < 8; ++c) {
                        float val = fmaxf(acc[c][r] + bias[c * 16 + m], 0.0f);
                        if (gl < HL)
                            atomicAdd(&hgloc[gl][c * 16 + m], val);
                        else
                            atomicAdd(&hg[(size_t)g * DIM + c * 16 + m], val);
                    }
                }
            }
        }
    }
    __syncthreads();
    for (int i = t; i < HL * DIM; i += 256) {
        float v = ((float*)hgloc)[i];
        int g = gid0 + (i >> 7);
        if (v != 0.0f && g < NG) atomicAdd(&hg[(size_t)g * DIM + (i & 127)], v);
    }
}

// ---------------- classifier: one block per graph, fused count ----------------
__global__ void classify_kernel(const float* __restrict__ hg, const int* __restrict__ gid,
                                const float* __restrict__ Wc, const float* __restrict__ bc,
                                float* __restrict__ out, int n) {
    __shared__ float inv;
    int g = blockIdx.x, t = threadIdx.x;
    if (t == 0) {
        int lo = 0, hi = n;
        while (lo < hi) { int mid = (lo + hi) >> 1; if (gid[mid] < g) lo = mid + 1; else hi = mid; }
        int lb = lo;
        lo = 0; hi = n;
        while (lo < hi) { int mid = (lo + hi) >> 1; if (gid[mid] <= g) lo = mid + 1; else hi = mid; }
        inv = 1.0f / fmaxf((float)(lo - lb), 1.0f);
    }
    __syncthreads();
    if (t < NCLS) {
        float s = 0.0f;
        for (int k = 0; k < DIM; ++k) s = fmaf(hg[g * DIM + k], Wc[k * NCLS + t], s);
        out[g * NCLS + t] = s * inv + bc[t];
    }
}

extern "C" void kernel_launch(void* const* d_in, const int* in_sizes, int n_in,
                              void* d_out, int out_size, void* d_ws, size_t ws_size,
                              hipStream_t stream) {
    const float* h   = (const float*)d_in[0];
    const int*   src = (const int*)d_in[1];
    const int*   dst = (const int*)d_in[2];
    const int*   gid = (const int*)d_in[3];
    const float* W1  = (const float*)d_in[4];
    const float* b1  = (const float*)d_in[5];
    const float* W2  = (const float*)d_in[6];
    const float* b2  = (const float*)d_in[7];
    const float* Wc  = (const float*)d_in[8];
    const float* bc  = (const float*)d_in[9];
    float* out = (float*)d_out;

    const int n = in_sizes[0] / DIM;   // 100000
    const int e = in_sizes[1];         // 1600000
    const int nw = (n + WSZ - 1) / WSZ;   // 391 windows

    char* ws = (char*)d_ws;
    size_t off = 0;
    auto alloc = [&](size_t bytes) -> char* {
        char* p = ws + off;
        off = (off + bytes + 255) & ~(size_t)255;
        return p;
    };
    int*   cnt_in  = (int*)alloc((size_t)n * 4);
    float* rs_in   = (float*)alloc((size_t)n * 4);
    float* rs_out  = (float*)alloc((size_t)n * 4);
    int*   curD    = (int*)alloc((size_t)2 * NWMAX * 4);   // curD + curS contiguous
    int*   curS    = curD + NWMAX;
    int*   colx_pad = (int*)alloc((size_t)n * CAP * 4);          // 25.6 MB
    int*   bucketD = (int*)alloc((size_t)nw * CAPB * 4);         // 12.8 MB
    unsigned char* bucketS = (unsigned char*)alloc((size_t)nw * CAPB);  // 3.2 MB
    float* hg      = (float*)alloc((size_t)NG * DIM * 4);
    unsigned short* Wt1 = (unsigned short*)alloc(128 * 128 * 2);
    unsigned short* Wt2 = (unsigned short*)alloc(128 * 128 * 2);
    uint4* hb4  = (uint4*)alloc((size_t)(n + 4) * 64 * 4);
    uint4* aggB = (uint4*)alloc((size_t)(n + 4) * 64 * 4);
    uint4* x1b4 = (uint4*)alloc((size_t)(n + 4) * 64 * 4);

    const int SPMM_B = (n + 3) / 4;
    const int MM_B = (n + 127) / 128;
    const int AB = (e + EPB - 1) / EPB;

    (void)hipMemsetAsync(curD, 0, (size_t)2 * NWMAX * 4, stream);

    bucket_kernel<<<AB, 1024, 0, stream>>>(src, dst, curD, curS, bucketD, bucketS,
                                           W1, W2, Wt1, Wt2, hg, hb4, x1b4, e, nw, n);
    window_kernel<<<nw, 1024, 0, stream>>>(curD, curS, bucketD, bucketS, h,
                                           cnt_in, rs_in, rs_out, colx_pad, hb4, n);

    // layer 1
    spmm_bf16<<<SPMM_B, 256, 0, stream>>>(hb4, cnt_in, colx_pad, rs_in, aggB, n);
    mm_mfma<<<MM_B, 256, 0, stream>>>((const unsigned char*)aggB, (const uint4*)Wt1,
                                      b1, rs_out, (unsigned short*)x1b4, n);
    // layer 2 + fused readout numerator
    spmm_bf16<<<SPMM_B, 256, 0, stream>>>(x1b4, cnt_in, colx_pad, rs_in, aggB, n);
    mm_mfma_readout<<<MM_B, 256, 0, stream>>>((const unsigned char*)aggB, (const uint4*)Wt2,
                                              b2, gid, hg, n);
    // classify (fused per-graph count)
    classify_kernel<<<NG, 64, 0, stream>>>(hg, gid, Wc, bc, out, n);
}

// Round 13
// 310.395 us; speedup vs baseline: 1.0309x; 1.0309x over previous
//
#include <hip/hip_runtime.h>

#define DIM 128
#define NG 64
#define NCLS 10
#define CAP 64             // padded-CSR slots per node
#define WSZ 256            // nodes per window
#define NWMAX 512          // max windows (n <= 131072)
#define CAPB 8192          // edges per window bucket (mean 4096, +64 sigma)
#define EPB 8192           // edges per bucket_kernel block (R11 value; 4096 regressed)
#define HL 4               // local readout accumulator graphs per block
#define WTP 68             // LDS Wt row stride in words (272 B: frag reads 2-way alias = free)

typedef __attribute__((ext_vector_type(8))) short s8v;
typedef __attribute__((ext_vector_type(4))) float f4v;

__device__ inline unsigned short f2bf(float f) {
    unsigned int u = __float_as_uint(f);
    unsigned int r = (u + 0x7fffu + ((u >> 16) & 1u)) >> 16;
    return (unsigned short)r;
}
__device__ inline unsigned int pack2bf(float a, float b) {
    return ((unsigned int)f2bf(b) << 16) | (unsigned int)f2bf(a);
}

// ---------------- Phase A: bucket edges (R11 config) + folded prep work ----------------
// 0-based cursors (4KB memset by host). First blocks also do the former prep_kernel work
// (Wt cast/transpose, hg zero, zero-row init) - saves one serialized dispatch.
__global__ __launch_bounds__(1024) void bucket_kernel(const int* __restrict__ src,
                                                      const int* __restrict__ dst,
                                                      int* curD, int* curS,
                                                      int* __restrict__ bucketD,
                                                      unsigned char* __restrict__ bucketS,
                                                      const float* __restrict__ W1,
                                                      const float* __restrict__ W2,
                                                      unsigned short* __restrict__ Wt1,
                                                      unsigned short* __restrict__ Wt2,
                                                      float* __restrict__ hg,
                                                      uint4* hb4, uint4* x1b4,
                                                      int e, int nw, int n) {
    __shared__ int histD[NWMAX];
    __shared__ int histS[NWMAX];
    int t = threadIdx.x;
    int gtid = blockIdx.x * 1024 + t;
    // folded prep (independent of bucketing; covered by first 32 blocks)
    if (gtid < 32768) {
        int which = gtid >> 14;
        int i = gtid & 16383;
        int c = i >> 7, k = i & 127;
        (which ? Wt2 : Wt1)[i] = f2bf((which ? W2 : W1)[k * 128 + c]);
    }
    if (gtid < NG * DIM) hg[gtid] = 0.0f;
    if (gtid < 16) {
        uint4 z = make_uint4(0, 0, 0, 0);
        hb4[(size_t)n * 16 + gtid] = z;
        x1b4[(size_t)n * 16 + gtid] = z;
    }
    for (int i = t; i < nw; i += 1024) { histD[i] = 0; histS[i] = 0; }
    __syncthreads();
    int lo = blockIdx.x * EPB;
    int hi = min(e, lo + EPB);
    for (int i = lo + t * 4; i < hi; i += 4096) {
        int4 d4 = *(const int4*)&dst[i];
        int4 s4 = *(const int4*)&src[i];
        atomicAdd(&histD[d4.x >> 8], 1); atomicAdd(&histS[s4.x >> 8], 1);
        atomicAdd(&histD[d4.y >> 8], 1); atomicAdd(&histS[s4.y >> 8], 1);
        atomicAdd(&histD[d4.z >> 8], 1); atomicAdd(&histS[s4.z >> 8], 1);
        atomicAdd(&histD[d4.w >> 8], 1); atomicAdd(&histS[s4.w >> 8], 1);
    }
    __syncthreads();
    for (int i = t; i < nw; i += 1024) {
        int hd = histD[i], hs = histS[i];
        histD[i] = hd ? atomicAdd(&curD[i], hd) : 0;   // 0-based within window
        histS[i] = hs ? atomicAdd(&curS[i], hs) : 0;
    }
    __syncthreads();
    for (int i = lo + t * 4; i < hi; i += 4096) {
        int4 d4 = *(const int4*)&dst[i];
        int4 s4 = *(const int4*)&src[i];
#pragma unroll
        for (int j = 0; j < 4; ++j) {
            int d = (&d4.x)[j], s = (&s4.x)[j];
            int sd = atomicAdd(&histD[d >> 8], 1);
            bucketD[(size_t)(d >> 8) * CAPB + sd] = (s << 8) | (d & 255);
            int ss = atomicAdd(&histS[s >> 8], 1);
            bucketS[(size_t)(s >> 8) * CAPB + ss] = (unsigned char)(s & 255);
        }
    }
}

// ---------------- Phase B: window CSR fill + degrees + rs + FUSED h cast; 512 threads ---------
__global__ __launch_bounds__(512) void window_kernel(const int* __restrict__ curD,
                                                     const int* __restrict__ curS,
                                                     const int* __restrict__ bucketD,
                                                     const unsigned char* __restrict__ bucketS,
                                                     const float* __restrict__ h,
                                                     int* __restrict__ cnt_in,
                                                     float* __restrict__ rs_in,
                                                     float* __restrict__ rs_out,
                                                     int* __restrict__ colx_pad,
                                                     uint4* __restrict__ hb4, int n) {
    __shared__ int cin[WSZ];
    __shared__ int cout[WSZ];
    __shared__ float rsO_s[WSZ];
    int w = blockIdx.x, t = threadIdx.x;
    if (t < WSZ) { cin[t] = 0; cout[t] = 0; }
    __syncthreads();
    size_t base = (size_t)w * CAPB;
    int nE = min(curD[w], CAPB);
    for (int i = t; i < nE; i += 512) {
        int v = bucketD[base + i];
        int d8 = v & 255;
        int slot = atomicAdd(&cin[d8], 1);
        if (slot < CAP) colx_pad[(((w << 8) + d8) << 6) + slot] = v >> 8;
    }
    int nS = min(curS[w], CAPB);
    for (int i = t; i < nS; i += 512) atomicAdd(&cout[bucketS[base + i]], 1);
    __syncthreads();
    if (t < WSZ) {
        int node = (w << 8) + t;
        if (node < n) {
            int c = cin[t];
            cnt_in[node] = c;
            rs_in[node] = rsqrtf(fmaxf((float)c, 1.0f));
            float ro = rsqrtf(fmaxf((float)cout[t], 1.0f));
            rs_out[node] = ro;
            rsO_s[t] = ro;
            int cc = min(c, CAP);
            int c8 = min((cc + 7) & ~7, CAP);   // pad to multiple of 8 (zero-row n)
            for (int s = cc; s < c8; ++s) colx_pad[((size_t)node << 6) + s] = n;
        }
    }
    __syncthreads();
    for (int idx = t; idx < WSZ * 16; idx += 512) {
        int rl = idx >> 4, sub = idx & 15;
        int nd = (w << 8) + rl;
        if (nd < n) {
            float s = rsO_s[rl];
            float4 a = ((const float4*)h)[(size_t)nd * 32 + sub * 2];
            float4 b = ((const float4*)h)[(size_t)nd * 32 + sub * 2 + 1];
            uint4 o;
            o.x = pack2bf(a.x * s, a.y * s);
            o.y = pack2bf(a.z * s, a.w * s);
            o.z = pack2bf(b.x * s, b.y * s);
            o.w = pack2bf(b.z * s, b.w * s);
            hb4[(size_t)nd * 16 + sub] = o;
        }
    }
}

// ---------------- SpMM gather, dwordx4, pad-8 slots (unchanged from R11) ----------------
__global__ __launch_bounds__(256) void spmm_bf16(const uint4* __restrict__ xb4,
                                                 const int* __restrict__ cnt_in,
                                                 const int* __restrict__ colx_pad,
                                                 const float* __restrict__ rs_in,
                                                 uint4* __restrict__ yb4, int n) {
    int node = (blockIdx.x * 256 + threadIdx.x) >> 6;
    int lane = threadIdx.x & 63;
    if (node >= n) return;
    int g = lane >> 4, sub = lane & 15;
    int cnt = min(cnt_in[node], CAP);
    int cnt8 = min((cnt + 7) & ~7, CAP);
    int myc = colx_pad[((size_t)node << 6) + ((lane < cnt8) ? lane : 0)];
    float acc[8] = {0.f, 0.f, 0.f, 0.f, 0.f, 0.f, 0.f, 0.f};
    int j = 0;
    for (; j + 16 <= cnt8; j += 16) {
        uint4 v[4];
#pragma unroll
        for (int b = 0; b < 4; ++b) {
            int c = __shfl(myc, j + 4 * b + g);
            v[b] = xb4[(size_t)c * 16 + sub];
        }
#pragma unroll
        for (int b = 0; b < 4; ++b) {
            acc[0] += __uint_as_float(v[b].x << 16);
            acc[1] += __uint_as_float(v[b].x & 0xffff0000u);
            acc[2] += __uint_as_float(v[b].y << 16);
            acc[3] += __uint_as_float(v[b].y & 0xffff0000u);
            acc[4] += __uint_as_float(v[b].z << 16);
            acc[5] += __uint_as_float(v[b].z & 0xffff0000u);
            acc[6] += __uint_as_float(v[b].w << 16);
            acc[7] += __uint_as_float(v[b].w & 0xffff0000u);
        }
    }
    if (j < cnt8) {
        int c0 = __shfl(myc, j + g);
        int c1 = __shfl(myc, j + 4 + g);
        uint4 v0 = xb4[(size_t)c0 * 16 + sub];
        uint4 v1 = xb4[(size_t)c1 * 16 + sub];
#pragma unroll
        for (int b = 0; b < 2; ++b) {
            uint4 v = b ? v1 : v0;
            acc[0] += __uint_as_float(v.x << 16);
            acc[1] += __uint_as_float(v.x & 0xffff0000u);
            acc[2] += __uint_as_float(v.y << 16);
            acc[3] += __uint_as_float(v.y & 0xffff0000u);
            acc[4] += __uint_as_float(v.z << 16);
            acc[5] += __uint_as_float(v.z & 0xffff0000u);
            acc[6] += __uint_as_float(v.w << 16);
            acc[7] += __uint_as_float(v.w & 0xffff0000u);
        }
    }
#pragma unroll
    for (int i = 0; i < 8; ++i) {
        acc[i] += __shfl_xor(acc[i], 16);
        acc[i] += __shfl_xor(acc[i], 32);
    }
    if (g == 0) {
        float w = rs_in[node];
        uint4 o;
        o.x = pack2bf(acc[0] * w, acc[1] * w);
        o.y = pack2bf(acc[2] * w, acc[3] * w);
        o.z = pack2bf(acc[4] * w, acc[5] * w);
        o.w = pack2bf(acc[6] * w, acc[7] * w);
        yb4[(size_t)node * 16 + sub] = o;
    }
}

// ---------------- stage Wt (32KB) into LDS with padded stride ----------------
__device__ inline void stage_wt(const uint4* __restrict__ Wt4, unsigned int* WtL, int t) {
#pragma unroll
    for (int i = 0; i < 8; ++i) {
        int q = t + 256 * i;           // 0..2047
        int row = q >> 4, col4 = q & 15;
        *(uint4*)&WtL[row * WTP + col4 * 4] = Wt4[q];
    }
}

// ---------------- layer-1 MM: 64 rows/block (R11 config) ----------------
__global__ __launch_bounds__(256) void mm_mfma(const unsigned char* __restrict__ A,
                                               const uint4* __restrict__ Wt4,
                                               const float* __restrict__ bias,
                                               const float* __restrict__ rs_out,
                                               unsigned short* __restrict__ out, int n) {
    __shared__ unsigned int WtL[128 * WTP];   // 34.8 KB
    int t = threadIdx.x;
    stage_wt(Wt4, WtL, t);
    int wave = t >> 6, lane = t & 63;
    int m = lane & 15, q = lane >> 4;
    int r0 = (int)blockIdx.x * 64 + wave * 16;
    int arow = min(r0 + m, n - 1);
    __syncthreads();
    f4v acc[8];
#pragma unroll
    for (int c = 0; c < 8; ++c) acc[c] = (f4v){0.f, 0.f, 0.f, 0.f};
#pragma unroll
    for (int k0 = 0; k0 < 4; ++k0) {
        s8v a = *(const s8v*)(A + (size_t)arow * 256 + k0 * 64 + q * 16);
#pragma unroll
        for (int c = 0; c < 8; ++c) {
            s8v b = *(const s8v*)&WtL[(c * 16 + m) * WTP + k0 * 16 + q * 4];
            acc[c] = __builtin_amdgcn_mfma_f32_16x16x32_bf16(a, b, acc[c], 0, 0, 0);
        }
    }
#pragma unroll
    for (int c = 0; c < 8; ++c) {
        float bv = bias[c * 16 + m];
#pragma unroll
        for (int r = 0; r < 4; ++r) {
            int row = r0 + q * 4 + r;
            if (row < n) {
                float val = fmaxf(acc[c][r] + bv, 0.0f);
                out[(size_t)row * 128 + c * 16 + m] = f2bf(val * rs_out[row]);
            }
        }
    }
}

// ---------------- layer-2 MM with FUSED mean-readout numerator (R11 config) ----------------
__global__ __launch_bounds__(256) void mm_mfma_readout(const unsigned char* __restrict__ A,
                                                       const uint4* __restrict__ Wt4,
                                                       const float* __restrict__ bias,
                                                       const int* __restrict__ gid,
                                                       float* __restrict__ hg, int n) {
    __shared__ unsigned int WtL[128 * WTP];   // 34.8 KB
    __shared__ float hgloc[HL][DIM];          // 2 KB
    int t = threadIdx.x;
    stage_wt(Wt4, WtL, t);
    for (int i = t; i < HL * DIM; i += 256) ((float*)hgloc)[i] = 0.0f;
    int wave = t >> 6, lane = t & 63;
    int m = lane & 15, q = lane >> 4;
    int r0 = (int)blockIdx.x * 64 + wave * 16;
    int b0 = (int)blockIdx.x * 64;
    int gid0 = gid[min(b0, n - 1)];
    int arow = min(r0 + m, n - 1);
    __syncthreads();
    f4v acc[8];
#pragma unroll
    for (int c = 0; c < 8; ++c) acc[c] = (f4v){0.f, 0.f, 0.f, 0.f};
#pragma unroll
    for (int k0 = 0; k0 < 4; ++k0) {
        s8v a = *(const s8v*)(A + (size_t)arow * 256 + k0 * 64 + q * 16);
#pragma unroll
        for (int c = 0; c < 8; ++c) {
            s8v b = *(const s8v*)&WtL[(c * 16 + m) * WTP + k0 * 16 + q * 4];
            acc[c] = __builtin_amdgcn_mfma_f32_16x16x32_bf16(a, b, acc[c], 0, 0, 0);
        }
    }
    int gfirst = gid[min(r0, n - 1)];
    int glast = gid[min(r0 + 15, n - 1)];
    bool uni = (gfirst == glast) && (r0 + 15 < n);
    if (uni) {
        int gl = gfirst - gid0;
#pragma unroll
        for (int c = 0; c < 8; ++c) {
            float bv = bias[c * 16 + m];
            float s = fmaxf(acc[c][0] + bv, 0.0f) + fmaxf(acc[c][1] + bv, 0.0f) +
                      fmaxf(acc[c][2] + bv, 0.0f) + fmaxf(acc[c][3] + bv, 0.0f);
            s += __shfl_xor(s, 16);
            s += __shfl_xor(s, 32);
            if (q == 0) {
                if (gl < HL)
                    atomicAdd(&hgloc[gl][c * 16 + m], s);
                else
                    atomicAdd(&hg[(size_t)gfirst * DIM + c * 16 + m], s);
            }
        }
    } else {
#pragma unroll
        for (int r = 0; r < 4; ++r) {
            int row = r0 + q * 4 + r;
            if (row < n) {
                int g = gid[row];
                int gl = g - gid0;
#pragma unroll
                for (int c = 0; c < 8; ++c) {
                    float val = fmaxf(acc[c][r] + bias[c * 16 + m], 0.0f);
                    if (gl < HL)
                        atomicAdd(&hgloc[gl][c * 16 + m], val);
                    else
                        atomicAdd(&hg[(size_t)g * DIM + c * 16 + m], val);
                }
            }
        }
    }
    __syncthreads();
    for (int i = t; i < HL * DIM; i += 256) {
        float v = ((float*)hgloc)[i];
        int g = gid0 + (i >> 7);
        if (v != 0.0f && g < NG) atomicAdd(&hg[(size_t)g * DIM + (i & 127)], v);
    }
}

// ---------------- classifier: one block per graph, fused count ----------------
__global__ void classify_kernel(const float* __restrict__ hg, const int* __restrict__ gid,
                                const float* __restrict__ Wc, const float* __restrict__ bc,
                                float* __restrict__ out, int n) {
    __shared__ float inv;
    int g = blockIdx.x, t = threadIdx.x;
    if (t == 0) {
        int lo = 0, hi = n;
        while (lo < hi) { int mid = (lo + hi) >> 1; if (gid[mid] < g) lo = mid + 1; else hi = mid; }
        int lb = lo;
        lo = 0; hi = n;
        while (lo < hi) { int mid = (lo + hi) >> 1; if (gid[mid] <= g) lo = mid + 1; else hi = mid; }
        inv = 1.0f / fmaxf((float)(lo - lb), 1.0f);
    }
    __syncthreads();
    if (t < NCLS) {
        float s = 0.0f;
        for (int k = 0; k < DIM; ++k) s = fmaf(hg[g * DIM + k], Wc[k * NCLS + t], s);
        out[g * NCLS + t] = s * inv + bc[t];
    }
}

extern "C" void kernel_launch(void* const* d_in, const int* in_sizes, int n_in,
                              void* d_out, int out_size, void* d_ws, size_t ws_size,
                              hipStream_t stream) {
    const float* h   = (const float*)d_in[0];
    const int*   src = (const int*)d_in[1];
    const int*   dst = (const int*)d_in[2];
    const int*   gid = (const int*)d_in[3];
    const float* W1  = (const float*)d_in[4];
    const float* b1  = (const float*)d_in[5];
    const float* W2  = (const float*)d_in[6];
    const float* b2  = (const float*)d_in[7];
    const float* Wc  = (const float*)d_in[8];
    const float* bc  = (const float*)d_in[9];
    float* out = (float*)d_out;

    const int n = in_sizes[0] / DIM;   // 100000
    const int e = in_sizes[1];         // 1600000
    const int nw = (n + WSZ - 1) / WSZ;   // 391 windows

    char* ws = (char*)d_ws;
    size_t off = 0;
    auto alloc = [&](size_t bytes) -> char* {
        char* p = ws + off;
        off = (off + bytes + 255) & ~(size_t)255;
        return p;
    };
    int*   cnt_in  = (int*)alloc((size_t)n * 4);
    float* rs_in   = (float*)alloc((size_t)n * 4);
    float* rs_out  = (float*)alloc((size_t)n * 4);
    int*   curD    = (int*)alloc((size_t)2 * NWMAX * 4);   // curD + curS contiguous
    int*   curS    = curD + NWMAX;
    int*   colx_pad = (int*)alloc((size_t)n * CAP * 4);          // 25.6 MB
    int*   bucketD = (int*)alloc((size_t)nw * CAPB * 4);         // 12.8 MB
    unsigned char* bucketS = (unsigned char*)alloc((size_t)nw * CAPB);  // 3.2 MB
    float* hg      = (float*)alloc((size_t)NG * DIM * 4);
    unsigned short* Wt1 = (unsigned short*)alloc(128 * 128 * 2);
    unsigned short* Wt2 = (unsigned short*)alloc(128 * 128 * 2);
    uint4* hb4  = (uint4*)alloc((size_t)(n + 4) * 64 * 4);
    uint4* aggB = (uint4*)alloc((size_t)(n + 4) * 64 * 4);
    uint4* x1b4 = (uint4*)alloc((size_t)(n + 4) * 64 * 4);

    const int SPMM_B = (n + 3) / 4;
    const int MM_B = (n + 63) / 64;
    const int AB = (e + EPB - 1) / EPB;

    (void)hipMemsetAsync(curD, 0, (size_t)2 * NWMAX * 4, stream);

    bucket_kernel<<<AB, 1024, 0, stream>>>(src, dst, curD, curS, bucketD, bucketS,
                                           W1, W2, Wt1, Wt2, hg, hb4, x1b4, e, nw, n);
    window_kernel<<<nw, 512, 0, stream>>>(curD, curS, bucketD, bucketS, h,
                                          cnt_in, rs_in, rs_out, colx_pad, hb4, n);

    // layer 1
    spmm_bf16<<<SPMM_B, 256, 0, stream>>>(hb4, cnt_in, colx_pad, rs_in, aggB, n);
    mm_mfma<<<MM_B, 256, 0, stream>>>((const unsigned char*)aggB, (const uint4*)Wt1,
                                      b1, rs_out, (unsigned short*)x1b4, n);
    // layer 2 + fused readout numerator
    spmm_bf16<<<SPMM_B, 256, 0, stream>>>(x1b4, cnt_in, colx_pad, rs_in, aggB, n);
    mm_mfma_readout<<<MM_B, 256, 0, stream>>>((const unsigned char*)aggB, (const uint4*)Wt2,
                                              b2, gid, hg, n);
    // classify (fused per-graph count)
    classify_kernel<<<NG, 64, 0, stream>>>(hg, gid, Wc, bc, out, n);
}